// Round 6
// baseline (54.666 us; speedup 1.0000x reference)
//
#include <hip/hip_runtime.h>
#include <hip/hip_bf16.h>
#include <stdint.h>

// Problem constants
#define B_DIM 8
#define T_DIM 2048
#define INNER 256      // IN_DIM == HEAD_TOTAL == 256
#define NEGV (-1e9f)
#define SCALE 0.0625f  // 1/sqrt(256)

typedef __bf16 bf16_t;
typedef __bf16 bf16x4_t __attribute__((ext_vector_type(4)));
typedef __bf16 bf16x8 __attribute__((ext_vector_type(8)));
typedef float f32x4 __attribute__((ext_vector_type(4)));

// ---- async global->LDS, 16B per lane (global_load_lds_dwordx4) ----
__device__ inline void gload_lds16(const bf16_t* g, bf16_t* lds) {
  __builtin_amdgcn_global_load_lds(
      (__attribute__((address_space(1))) void*)(g),
      (__attribute__((address_space(3))) void*)(lds),
      16, 0, 0);
}

// Stage a 128x64 bf16 tile (row stride ldg elements) into lds[128][64].
// Linear LDS layout; wave-uniform LDS base + lane*16 (HW requirement).
__device__ inline void stage_tile(const bf16_t* gbase, int ldg,
                                  bf16_t (*lds)[64], int tid) {
  const int l = tid & 63;
  const int w = tid >> 6;
  const int sub = l >> 3;        // row within 8-row chunk
  const int ce = (l & 7) * 8;    // starting column element (8 bf16 = 16B)
#pragma unroll
  for (int i = 0; i < 4; ++i) {
    const int chunk = i * 4 + w;               // 0..15, uniform per wave
    const int row = chunk * 8 + sub;
    gload_lds16(gbase + (size_t)row * ldg + ce, &lds[chunk * 8][0]);
  }
}

// 128x128 output tile GEMM, C = A * B^T, both A and Bm are [row][k] bf16.
// Single-buffered m97 structure (32KB LDS; TLP hides staging latency better
// than explicit dbuf at K=256 [round-3 post-mortem]).
// 256 threads = 4 waves in 2x2; each wave owns a 64x64 sub-tile (4x4 frags).
template <int KDIM>
__device__ inline void gemm_bt_128(const bf16_t* A, const bf16_t* Bm, int ld,
                                   bf16_t (*Al)[64], bf16_t (*Bl)[64],
                                   f32x4 acc[4][4], int tid) {
  const int l = tid & 63;
  const int wid = tid >> 6;
  const int wr = wid >> 1, wc = wid & 1;
  const int lr = l & 15;   // fragment row (A) / col (B) lane
  const int kg = l >> 4;   // k-chunk group 0..3
#pragma unroll
  for (int k0 = 0; k0 < KDIM; k0 += 64) {
    stage_tile(A + k0, ld, Al, tid);
    stage_tile(Bm + k0, ld, Bl, tid);
    __syncthreads();   // compiler drains vmcnt(0) before s_barrier
#pragma unroll
    for (int kk = 0; kk < 2; ++kk) {
      bf16x8 af[4], bfm[4];
#pragma unroll
      for (int f = 0; f < 4; ++f) {
        af[f]  = *(const bf16x8*)&Al[wr * 64 + f * 16 + lr][kk * 32 + kg * 8];
        bfm[f] = *(const bf16x8*)&Bl[wc * 64 + f * 16 + lr][kk * 32 + kg * 8];
      }
#pragma unroll
      for (int m = 0; m < 4; ++m)
#pragma unroll
        for (int n = 0; n < 4; ++n)
          acc[m][n] = __builtin_amdgcn_mfma_f32_16x16x32_bf16(
              af[m], bfm[n], acc[m][n], 0, 0, 0);
    }
    __syncthreads();
  }
}

// ---- Kernel 0: fp32->bf16 converts only (~25 MB traffic) ----
// Blocks [0, 2048): convert x, grid-stride. Blocks [2048, 2176): Wq/Wk.
__global__ __launch_bounds__(256) void prep_kernel(
    const float* __restrict__ x, const float* __restrict__ Wq,
    const float* __restrict__ Wk, bf16_t* __restrict__ xb,
    bf16_t* __restrict__ Wqb, bf16_t* __restrict__ Wkb) {
  const int bid = blockIdx.x;
  const int tid = threadIdx.x;
  if (bid < 2048) {
    const int n4 = (B_DIM * T_DIM * INNER) / 4;        // 1,048,576 float4
    for (int i = bid * 256 + tid; i < n4; i += 2048 * 256) {
      f32x4 v = *(const f32x4*)&x[(size_t)i * 4];
      bf16x4_t o;
      o[0] = (bf16_t)v[0]; o[1] = (bf16_t)v[1];
      o[2] = (bf16_t)v[2]; o[3] = (bf16_t)v[3];
      *(bf16x4_t*)&xb[(size_t)i * 4] = o;
    }
  } else {
    const int b2 = bid - 2048;                         // 0..127
    const float* src = (b2 < 64) ? Wq : Wk;
    bf16_t* dst = (b2 < 64) ? Wqb : Wkb;
    const int i = (b2 & 63) * 256 + tid;               // 16384 float4 total
    f32x4 v = *(const f32x4*)&src[(size_t)i * 4];
    bf16x4_t o;
    o[0] = (bf16_t)v[0]; o[1] = (bf16_t)v[1];
    o[2] = (bf16_t)v[2]; o[3] = (bf16_t)v[3];
    *(bf16x4_t*)&dst[(size_t)i * 4] = o;
  }
}

// ---- Kernel 1: Q = xb @ Wqb^T, K = xb @ Wkb^T (bf16 out to workspace) ----
__global__ __launch_bounds__(256) void proj_kernel(
    const bf16_t* __restrict__ x, const bf16_t* __restrict__ Wq,
    const bf16_t* __restrict__ Wk, bf16_t* __restrict__ Q,
    bf16_t* __restrict__ Kout) {
  __shared__ bf16_t Al[128][64];
  __shared__ bf16_t Bl[128][64];
  const int tid = threadIdx.x;
  const int mrow = blockIdx.x * 128;   // row in [0, B*T)
  const int ncol = blockIdx.y * 128;   // out-feature
  const bf16_t* W = blockIdx.z ? Wk : Wq;
  bf16_t* O = blockIdx.z ? Kout : Q;

  f32x4 acc[4][4] = {};
  gemm_bt_128<INNER>(x + (size_t)mrow * INNER, W + (size_t)ncol * INNER,
                     INNER, Al, Bl, acc, tid);

  const int l = tid & 63, wid = tid >> 6, wr = wid >> 1, wc = wid & 1;
  const int lr = l & 15, kg = l >> 4;
#pragma unroll
  for (int m = 0; m < 4; ++m)
#pragma unroll
    for (int n = 0; n < 4; ++n)
#pragma unroll
      for (int j = 0; j < 4; ++j) {
        // C/D layout: col = lane&15, row = (lane>>4)*4 + reg  [m89]
        int r = mrow + wr * 64 + m * 16 + kg * 4 + j;
        int c = ncol + wc * 64 + n * 16 + lr;
        O[(size_t)r * INNER + c] = (bf16_t)acc[m][n][j];
      }
}

// ---- Kernel 2: E = Q @ K^T * scale (+ diag mask); lower tiles fill -1e9 ----
// 1-D grid, 2048 blocks. XCD swizzle: `b = bid & 7` pins each batch's tiles
// to one XCD (Q_b + K_b = 2 MB fits the 4 MiB per-XCD L2). Epilogue goes
// through an LDS transpose so global stores are fully-coalesced f32x4
// (fragment-layout scalar stores were 64B segments -> ~3.4 TB/s effective;
// fill blocks prove 6.8 TB/s is available).
__global__ __launch_bounds__(256) void scores_kernel(
    const bf16_t* __restrict__ Q, const bf16_t* __restrict__ Kin,
    float* __restrict__ E) {
  const int bid = blockIdx.x;
  const int b = bid & 7;       // batch == XCD
  const int lid = bid >> 3;    // 0..255 tile id within batch
  const int rt = lid >> 4;     // row tile (t)
  const int ct = lid & 15;     // col tile (s)
  const int tid = threadIdx.x;
  float* Eb = E + (size_t)b * T_DIM * T_DIM;
  const int trow = rt * 128, scol = ct * 128;

  if (ct < rt) {
    // strictly below diagonal: exact -1e9 fill (512B row segments)
    const f32x4 neg = {NEGV, NEGV, NEGV, NEGV};
#pragma unroll
    for (int it = 0; it < 16; ++it) {
      int idx = it * 256 + tid;          // 0..4095 float4 slots
      int r = idx >> 5, c4 = idx & 31;
      *(f32x4*)&Eb[(size_t)(trow + r) * T_DIM + scol + c4 * 4] = neg;
    }
    return;
  }

  // Staging LDS for the K-loop; reused as padded f32 transpose buffer in the
  // epilogue. Pad 132: row stride 528B is 16B-aligned (aligned b128 reads);
  // write-in bank aliasing <=2-way (free, m136).
  __shared__ union SM {
    struct { bf16_t Al[128][64]; bf16_t Bl[128][64]; } g;
    float c[64][132];
  } sm;

  f32x4 acc[4][4] = {};
  const bf16_t* Qb = Q + (size_t)b * T_DIM * INNER;
  const bf16_t* Kb = Kin + (size_t)b * T_DIM * INNER;
  gemm_bt_128<INNER>(Qb + (size_t)trow * INNER, Kb + (size_t)scol * INNER,
                     INNER, sm.g.Al, sm.g.Bl, acc, tid);

  const int l = tid & 63, wid = tid >> 6, wr = wid >> 1, wc = wid & 1;
  const int lr = l & 15, kg = l >> 4;
  const bool diag = (ct == rt);

  // Two 64-row passes: scatter acc (scale+mask folded) into LDS, then stream
  // out as coalesced f32x4 (each wave stores 1KB contiguous per instr).
#pragma unroll
  for (int p = 0; p < 2; ++p) {
    __syncthreads();           // previous LDS use (K-loop / pass-0 reads) done
    if (wr == p) {
#pragma unroll
      for (int m = 0; m < 4; ++m)
#pragma unroll
        for (int n = 0; n < 4; ++n)
#pragma unroll
          for (int j = 0; j < 4; ++j) {
            int rl = m * 16 + kg * 4 + j;            // row within half: 0..63
            int c = wc * 64 + n * 16 + lr;           // col within tile: 0..127
            float v = acc[m][n][j] * SCALE;
            if (diag && c < p * 64 + rl) v += NEGV;  // s < t (scol==trow)
            sm.c[rl][c] = v;
          }
    }
    __syncthreads();
#pragma unroll
    for (int it = 0; it < 8; ++it) {
      int idx = it * 256 + tid;                      // 2048 f32x4 slots
      int r = idx >> 5, c4 = idx & 31;
      f32x4 v = *(const f32x4*)&sm.c[r][c4 * 4];
      *(f32x4*)&Eb[(size_t)(trow + p * 64 + r) * T_DIM + scol + c4 * 4] = v;
    }
  }
}

extern "C" void kernel_launch(void* const* d_in, const int* in_sizes, int n_in,
                              void* d_out, int out_size, void* d_ws,
                              size_t ws_size, hipStream_t stream) {
  const float* x  = (const float*)d_in[0];   // [8,2048,256] fp32
  const float* Wq = (const float*)d_in[1];   // [256,256] fp32
  const float* Wk = (const float*)d_in[2];   // [256,256] fp32
  float* out = (float*)d_out;

  const size_t n_x = (size_t)B_DIM * T_DIM * INNER;  // 4,194,304
  const size_t n_w = (size_t)INNER * INNER;          // 65,536

  // Workspace layout (bf16): xb | Wqb | Wkb | Q | K  (~25.4 MB)
  bf16_t* xb  = (bf16_t*)d_ws;
  bf16_t* Wqb = xb + n_x;
  bf16_t* Wkb = Wqb + n_w;
  bf16_t* Q   = Wkb + n_w;
  bf16_t* K   = Q + n_x;

  prep_kernel<<<2048 + 128, 256, 0, stream>>>(x, Wq, Wk, xb, Wqb, Wkb);

  dim3 g1(B_DIM * T_DIM / 128, INNER / 128, 2);  // (128, 2, 2)
  proj_kernel<<<g1, dim3(256), 0, stream>>>(xb, Wqb, Wkb, Q, K);

  scores_kernel<<<2048, 256, 0, stream>>>(Q, K, out);
}

// Round 7
// 47.084 us; speedup vs baseline: 1.1610x; 1.1610x over previous
//
#include <hip/hip_runtime.h>
#include <hip/hip_bf16.h>
#include <stdint.h>

// Problem constants
#define B_DIM 8
#define T_DIM 2048
#define INNER 256      // IN_DIM == HEAD_TOTAL == 256
#define NEGV (-1e9f)
#define SCALE 0.0625f  // 1/sqrt(256)

typedef __bf16 bf16_t;
typedef __bf16 bf16x8 __attribute__((ext_vector_type(8)));
typedef float f32x4 __attribute__((ext_vector_type(4)));

// ---- async global->LDS, 16B per lane (global_load_lds_dwordx4) ----
__device__ inline void gload_lds16(const bf16_t* g, bf16_t* lds) {
  __builtin_amdgcn_global_load_lds(
      (__attribute__((address_space(1))) void*)(g),
      (__attribute__((address_space(3))) void*)(lds),
      16, 0, 0);
}

// Stage a 128x64 bf16 tile (row stride ldg elements) into lds[128][64].
// Linear LDS layout; wave-uniform LDS base + lane*16 (HW requirement).
__device__ inline void stage_tile(const bf16_t* gbase, int ldg,
                                  bf16_t (*lds)[64], int tid) {
  const int l = tid & 63;
  const int w = tid >> 6;
  const int sub = l >> 3;        // row within 8-row chunk
  const int ce = (l & 7) * 8;    // starting column element (8 bf16 = 16B)
#pragma unroll
  for (int i = 0; i < 4; ++i) {
    const int chunk = i * 4 + w;               // 0..15, uniform per wave
    const int row = chunk * 8 + sub;
    gload_lds16(gbase + (size_t)row * ldg + ce, &lds[chunk * 8][0]);
  }
}

// Stage a 128x64 tile from FP32 global into bf16 LDS (reg-staged convert).
// Issue all 8 global loads first (latency overlap), then cvt + ds_write.
__device__ inline void stage_tile_cvt(const float* gbase, int ldg,
                                      bf16_t (*lds)[64], int tid) {
  const int l = tid & 63;
  const int w = tid >> 6;
  const int sub = l >> 3;
  const int ce = (l & 7) * 8;
  f32x4 v[4][2];
#pragma unroll
  for (int i = 0; i < 4; ++i) {
    const int row = (i * 4 + w) * 8 + sub;
    const float* p = gbase + (size_t)row * ldg + ce;
    v[i][0] = *(const f32x4*)p;
    v[i][1] = *(const f32x4*)(p + 4);
  }
#pragma unroll
  for (int i = 0; i < 4; ++i) {
    const int row = (i * 4 + w) * 8 + sub;
    bf16x8 o;
#pragma unroll
    for (int j = 0; j < 4; ++j) {
      o[j]     = (bf16_t)v[i][0][j];
      o[4 + j] = (bf16_t)v[i][1][j];
    }
    *(bf16x8*)&lds[row][ce] = o;
  }
}

// 128x128 output tile GEMM, C = A * B^T, both A and Bm are [row][k] bf16.
// Single-buffered m97 structure (32KB LDS; TLP hides staging latency better
// than explicit dbuf at K=256 [round-3 post-mortem]).
// 256 threads = 4 waves in 2x2; each wave owns a 64x64 sub-tile (4x4 frags).
template <int KDIM>
__device__ inline void gemm_bt_128(const bf16_t* A, const bf16_t* Bm, int ld,
                                   bf16_t (*Al)[64], bf16_t (*Bl)[64],
                                   f32x4 acc[4][4], int tid) {
  const int l = tid & 63;
  const int wid = tid >> 6;
  const int wr = wid >> 1, wc = wid & 1;
  const int lr = l & 15;   // fragment row (A) / col (B) lane
  const int kg = l >> 4;   // k-chunk group 0..3
#pragma unroll
  for (int k0 = 0; k0 < KDIM; k0 += 64) {
    stage_tile(A + k0, ld, Al, tid);
    stage_tile(Bm + k0, ld, Bl, tid);
    __syncthreads();   // compiler drains vmcnt(0) before s_barrier
#pragma unroll
    for (int kk = 0; kk < 2; ++kk) {
      bf16x8 af[4], bfm[4];
#pragma unroll
      for (int f = 0; f < 4; ++f) {
        af[f]  = *(const bf16x8*)&Al[wr * 64 + f * 16 + lr][kk * 32 + kg * 8];
        bfm[f] = *(const bf16x8*)&Bl[wc * 64 + f * 16 + lr][kk * 32 + kg * 8];
      }
#pragma unroll
      for (int m = 0; m < 4; ++m)
#pragma unroll
        for (int n = 0; n < 4; ++n)
          acc[m][n] = __builtin_amdgcn_mfma_f32_16x16x32_bf16(
              af[m], bfm[n], acc[m][n], 0, 0, 0);
    }
    __syncthreads();
  }
}

// ---- Kernel 1: Q = x @ Wq^T, K = x @ Wk^T, reading FP32 inputs directly ----
// fp32->bf16 conversion fused into the staging path (prep kernel deleted:
// saves 25 MB convert traffic + one launch + one dependency drain).
__global__ __launch_bounds__(256) void proj_kernel(
    const float* __restrict__ x, const float* __restrict__ Wq,
    const float* __restrict__ Wk, bf16_t* __restrict__ Q,
    bf16_t* __restrict__ Kout) {
  __shared__ bf16_t Al[128][64];
  __shared__ bf16_t Bl[128][64];
  const int tid = threadIdx.x;
  const int mrow = blockIdx.x * 128;   // row in [0, B*T)
  const int ncol = blockIdx.y * 128;   // out-feature
  const float* W = blockIdx.z ? Wk : Wq;
  bf16_t* O = blockIdx.z ? Kout : Q;

  const int l = tid & 63, wid = tid >> 6, wr = wid >> 1, wc = wid & 1;
  const int lr = l & 15, kg = l >> 4;

  f32x4 acc[4][4] = {};
  const float* Ax = x + (size_t)mrow * INNER;
  const float* Bw = W + (size_t)ncol * INNER;
#pragma unroll
  for (int k0 = 0; k0 < INNER; k0 += 64) {
    stage_tile_cvt(Ax + k0, INNER, Al, tid);
    stage_tile_cvt(Bw + k0, INNER, Bl, tid);
    __syncthreads();
#pragma unroll
    for (int kk = 0; kk < 2; ++kk) {
      bf16x8 af[4], bfm[4];
#pragma unroll
      for (int f = 0; f < 4; ++f) {
        af[f]  = *(const bf16x8*)&Al[wr * 64 + f * 16 + lr][kk * 32 + kg * 8];
        bfm[f] = *(const bf16x8*)&Bl[wc * 64 + f * 16 + lr][kk * 32 + kg * 8];
      }
#pragma unroll
      for (int m = 0; m < 4; ++m)
#pragma unroll
        for (int n = 0; n < 4; ++n)
          acc[m][n] = __builtin_amdgcn_mfma_f32_16x16x32_bf16(
              af[m], bfm[n], acc[m][n], 0, 0, 0);
    }
    __syncthreads();
  }

#pragma unroll
  for (int m = 0; m < 4; ++m)
#pragma unroll
    for (int n = 0; n < 4; ++n)
#pragma unroll
      for (int j = 0; j < 4; ++j) {
        // C/D layout: col = lane&15, row = (lane>>4)*4 + reg  [m89]
        int r = mrow + wr * 64 + m * 16 + kg * 4 + j;
        int c = ncol + wc * 64 + n * 16 + lr;
        O[(size_t)r * INNER + c] = (bf16_t)acc[m][n][j];
      }
}

// ---- Kernel 2: E = Q @ K^T * scale (+ diag mask); lower tiles fill -1e9 ----
// 1-D grid, 2048 blocks. XCD swizzle: default dispatch round-robins
// blockIdx.x across the 8 XCDs, so `b = bid & 7` pins each batch's tiles to
// one XCD; Q_b + K_b = 2 MB fits the 4 MiB per-XCD L2. Scalar fragment
// stores (round-6 LDS-transpose epilogue regressed: L2 aggregates 64B
// segments into lines; the extra barriers cost ~3.5us).
__global__ __launch_bounds__(256) void scores_kernel(
    const bf16_t* __restrict__ Q, const bf16_t* __restrict__ Kin,
    float* __restrict__ E) {
  const int bid = blockIdx.x;
  const int b = bid & 7;       // batch == XCD
  const int lid = bid >> 3;    // 0..255 tile id within batch
  const int rt = lid >> 4;     // row tile (t)
  const int ct = lid & 15;     // col tile (s)
  const int tid = threadIdx.x;
  float* Eb = E + (size_t)b * T_DIM * T_DIM;
  const int trow = rt * 128, scol = ct * 128;

  if (ct < rt) {
    // strictly below diagonal: exact -1e9 fill (512B row segments)
    const f32x4 neg = {NEGV, NEGV, NEGV, NEGV};
#pragma unroll
    for (int it = 0; it < 16; ++it) {
      int idx = it * 256 + tid;          // 0..4095 float4 slots
      int r = idx >> 5, c4 = idx & 31;
      *(f32x4*)&Eb[(size_t)(trow + r) * T_DIM + scol + c4 * 4] = neg;
    }
    return;
  }

  __shared__ bf16_t Al[128][64];
  __shared__ bf16_t Bl[128][64];
  f32x4 acc[4][4] = {};
  const bf16_t* Qb = Q + (size_t)b * T_DIM * INNER;
  const bf16_t* Kb = Kin + (size_t)b * T_DIM * INNER;
  gemm_bt_128<INNER>(Qb + (size_t)trow * INNER, Kb + (size_t)scol * INNER,
                     INNER, Al, Bl, acc, tid);

  const int l = tid & 63, wid = tid >> 6, wr = wid >> 1, wc = wid & 1;
  const int lr = l & 15, kg = l >> 4;
  const bool diag = (ct == rt);
#pragma unroll
  for (int m = 0; m < 4; ++m)
#pragma unroll
    for (int n = 0; n < 4; ++n)
#pragma unroll
      for (int j = 0; j < 4; ++j) {
        int t = trow + wr * 64 + m * 16 + kg * 4 + j;
        int s = scol + wc * 64 + n * 16 + lr;
        float v = acc[m][n][j] * SCALE;
        if (diag && s < t) v += NEGV;
        Eb[(size_t)t * T_DIM + s] = v;
      }
}

extern "C" void kernel_launch(void* const* d_in, const int* in_sizes, int n_in,
                              void* d_out, int out_size, void* d_ws,
                              size_t ws_size, hipStream_t stream) {
  const float* x  = (const float*)d_in[0];   // [8,2048,256] fp32
  const float* Wq = (const float*)d_in[1];   // [256,256] fp32
  const float* Wk = (const float*)d_in[2];   // [256,256] fp32
  float* out = (float*)d_out;

  const size_t n_x = (size_t)B_DIM * T_DIM * INNER;  // 4,194,304

  // Workspace layout (bf16): Q | K  (16.8 MB)
  bf16_t* Q = (bf16_t*)d_ws;
  bf16_t* K = Q + n_x;

  dim3 g1(B_DIM * T_DIM / 128, INNER / 128, 2);  // (128, 2, 2) = 512 blocks
  proj_kernel<<<g1, dim3(256), 0, stream>>>(x, Wq, Wk, Q, K);

  scores_kernel<<<2048, 256, 0, stream>>>(Q, K, out);
}